// Round 1
// baseline (611.463 us; speedup 1.0000x reference)
//
#include <hip/hip_runtime.h>
#include <stdint.h>

// JAX >= 0.4.30 defaults jax_threefry_partitionable=True. If validation fails
// with O(1-10) absmax, flip this to 0 (old split-counter random_bits path).
#define THREEFRY_PARTITIONABLE 1

__host__ __device__ inline void tf2x32(uint32_t k0, uint32_t k1,
                                       uint32_t x0, uint32_t x1,
                                       uint32_t* o0, uint32_t* o1) {
  const uint32_t ks2 = k0 ^ k1 ^ 0x1BD11BDAu;
#define ROTL(v, s) (((v) << (s)) | ((v) >> (32 - (s))))
#define RND(r) do { x0 += x1; x1 = ROTL(x1, r); x1 ^= x0; } while (0)
  x0 += k0; x1 += k1;
  RND(13); RND(15); RND(26); RND(6);
  x0 += k1; x1 += ks2 + 1u;
  RND(17); RND(29); RND(16); RND(24);
  x0 += ks2; x1 += k0 + 2u;
  RND(13); RND(15); RND(26); RND(6);
  x0 += k0; x1 += k1 + 3u;
  RND(17); RND(29); RND(16); RND(24);
  x0 += k1; x1 += ks2 + 4u;
  RND(13); RND(15); RND(26); RND(6);
  x0 += ks2; x1 += k0 + 5u;
  *o0 = x0; *o1 = x1;
#undef RND
#undef ROTL
}

// keep iff uniform(key)[idx] < 0.4  (bernoulli(key, 1-p), p=0.6)
__device__ inline bool drop_keep(uint32_t k0, uint32_t k1, uint32_t idx, uint32_t half) {
  uint32_t o0, o1, bits;
#if THREEFRY_PARTITIONABLE
  (void)half;
  tf2x32(k0, k1, 0u, idx, &o0, &o1);
  bits = o0 ^ o1;
#else
  if (idx < half) { tf2x32(k0, k1, idx, idx + half, &o0, &o1); bits = o0; }
  else            { tf2x32(k0, k1, idx - half, idx, &o0, &o1); bits = o1; }
#endif
  float u = __uint_as_float((bits >> 9) | 0x3f800000u) - 1.0f;
  return u < 0.4f;
}

__global__ void k_deg(const int* __restrict__ row, int* __restrict__ deg, int e) {
  int i = blockIdx.x * 256 + threadIdx.x;
  if (i < e) atomicAdd(&deg[row[i]], 1);
}

__global__ void k_dis(const int* __restrict__ deg, float* __restrict__ dis, int n) {
  int i = blockIdx.x * 256 + threadIdx.x;
  if (i < n) {
    int d = deg[i];
    dis[i] = d > 0 ? rsqrtf((float)d) : 0.0f;
  }
}

// inclusive scan of 256-chunks; chunk scans into rp[i+1], block totals into blksum
__global__ void k_scan_block(const int* __restrict__ deg, int* __restrict__ rp,
                             int* __restrict__ blksum, int n) {
  __shared__ int sm[256];
  int i = blockIdx.x * 256 + threadIdx.x;
  int v = (i < n) ? deg[i] : 0;
  sm[threadIdx.x] = v;
  __syncthreads();
  for (int off = 1; off < 256; off <<= 1) {
    int t = (threadIdx.x >= off) ? sm[threadIdx.x - off] : 0;
    __syncthreads();
    sm[threadIdx.x] += t;
    __syncthreads();
  }
  if (i < n) rp[i + 1] = sm[threadIdx.x];
  if (threadIdx.x == 255) blksum[blockIdx.x] = sm[255];
}

// exclusive scan of block sums (nblk <= 256), in place
__global__ void k_scan_top(int* __restrict__ blk, int nblk) {
  __shared__ int sm[256];
  int v = (threadIdx.x < nblk) ? blk[threadIdx.x] : 0;
  sm[threadIdx.x] = v;
  __syncthreads();
  for (int off = 1; off < 256; off <<= 1) {
    int t = (threadIdx.x >= off) ? sm[threadIdx.x - off] : 0;
    __syncthreads();
    sm[threadIdx.x] += t;
    __syncthreads();
  }
  if (threadIdx.x < nblk) blk[threadIdx.x] = sm[threadIdx.x] - v;
}

__global__ void k_scan_add(int* __restrict__ rp, const int* __restrict__ blk, int n) {
  int i = blockIdx.x * 256 + threadIdx.x;
  if (i == 0) rp[0] = 0;
  if (i < n) rp[i + 1] += blk[i >> 8];
}

// CSR fill: interleaved (col, weight) pairs; w = -dis[row]*dis[col]
__global__ void k_fill(const int* __restrict__ row, const int* __restrict__ col,
                       const float* __restrict__ dis, const int* __restrict__ rp,
                       int* __restrict__ cur, int2* __restrict__ cw, int e) {
  int i = blockIdx.x * 256 + threadIdx.x;
  if (i < e) {
    int r = row[i], c = col[i];
    int pos = rp[r] + atomicAdd(&cur[r], 1);
    float w = -dis[r] * dis[c];
    cw[pos] = make_int2(c, __float_as_int(w));
  }
}

// standalone dropout for layer 0 input
__global__ void k_drop(const float* __restrict__ x, float* __restrict__ y,
                       uint32_t k0, uint32_t k1, int n, uint32_t half) {
  int i = blockIdx.x * 256 + threadIdx.x;
  if (i < n) y[i] = drop_keep(k0, k1, (uint32_t)i, half) ? x[i] * 2.5f : 0.0f;
}

// Fused: Tx1 = L_hat @ xd (CSR gather, 1 wave per node), then
// out = xd@W[0] + Tx1@W[1] + b, optional relu, optional NEXT-layer dropout.
template<int COUT, bool RELU, bool DROPN>
__global__ __launch_bounds__(256) void k_conv(
    const float* __restrict__ xd, const int* __restrict__ rp,
    const int2* __restrict__ cw, const float* __restrict__ W,
    const float* __restrict__ b, float* __restrict__ out,
    uint32_t nk0, uint32_t nk1, uint32_t half, int n) {
  __shared__ float Ws[2 * 64 * COUT];
  __shared__ float xs[4][64];
  __shared__ float ps[4][64];
  for (int i = threadIdx.x; i < 2 * 64 * COUT; i += 256) Ws[i] = W[i];
  const int row0 = blockIdx.x * 4;
  const int rl = threadIdx.x >> 6;   // local row (one wave per row)
  const int t  = threadIdx.x & 63;   // feature lane
  const int r  = row0 + rl;
  if (r < n) {
    xs[rl][t] = xd[(size_t)r * 64 + t];
    float acc = 0.0f;
    const int e1 = rp[r + 1];
    for (int ee = rp[r]; ee < e1; ++ee) {
      int2 v = cw[ee];                 // wave-uniform 8B load
      acc += __int_as_float(v.y) * xd[(size_t)v.x * 64 + t];  // 256B coalesced gather
    }
    ps[rl][t] = acc;
  }
  __syncthreads();
  if (threadIdx.x < 4 * COUT) {
    const int rl2 = threadIdx.x / COUT;
    const int o   = threadIdx.x % COUT;
    const int rr  = row0 + rl2;
    if (rr < n) {
      float v = b[o];
      const float* W0s = Ws;
      const float* W1s = Ws + 64 * COUT;
      #pragma unroll
      for (int k = 0; k < 64; ++k) {
        v = fmaf(xs[rl2][k], W0s[k * COUT + o], v);
        v = fmaf(ps[rl2][k], W1s[k * COUT + o], v);
      }
      if (RELU) v = fmaxf(v, 0.0f);
      if (DROPN) {  // only instantiated with COUT==64
        if (drop_keep(nk0, nk1, (uint32_t)(rr * 64 + o), half)) v *= 2.5f;
        else v = 0.0f;
      }
      out[(size_t)rr * COUT + o] = v;
    }
  }
}

extern "C" void kernel_launch(void* const* d_in, const int* in_sizes, int n_in,
                              void* d_out, int out_size, void* d_ws, size_t ws_size,
                              hipStream_t stream) {
  const float* x   = (const float*)d_in[0];
  const int*   ei  = (const int*)d_in[1];
  const float* W0  = (const float*)d_in[2];
  const float* b0  = (const float*)d_in[3];
  const float* W1f = (const float*)d_in[4];
  const float* b1  = (const float*)d_in[5];
  const float* W2  = (const float*)d_in[6];
  const float* b2  = (const float*)d_in[7];
  float* out = (float*)d_out;

  const int n = in_sizes[0] / 64;   // 50000
  const int e = in_sizes[1] / 2;    // 800000
  const int* row = ei;
  const int* col = ei + e;
  const uint32_t half = (uint32_t)((size_t)n * 64 / 2);

  // workspace carve: 4B units, regions padded to 1KB. Total ~32.8 MB.
  size_t off = 0;
  auto carve = [&](size_t elems) {
    size_t o = off;
    off += (elems + 255) & ~(size_t)255;
    return o;
  };
  int* base = (int*)d_ws;
  int*   deg = base + carve(n);
  float* dis = (float*)(base + carve(n));
  int*   rp  = base + carve((size_t)n + 1);
  int*   cur = base + carve(n);
  int*   blk = base + carve(256);
  int2*  cw  = (int2*)(base + carve((size_t)e * 2));
  float* xa  = (float*)(base + carve((size_t)n * 64));
  float* xb  = (float*)(base + carve((size_t)n * 64));
  (void)ws_size;

  // dropout keys: fold_in(jax.random.key(1), i) = threefry2x32([0,1],[0,i])
  uint32_t dk[3][2];
  for (uint32_t i = 0; i < 3; ++i) tf2x32(0u, 1u, 0u, i, &dk[i][0], &dk[i][1]);

  hipMemsetAsync(deg, 0, (size_t)n * 4, stream);
  hipMemsetAsync(cur, 0, (size_t)n * 4, stream);

  const int be = (e + 255) / 256;      // 3125
  const int bn = (n + 255) / 256;      // 196
  const int bd = ((n * 64) + 255) / 256;
  const int bc = (n + 3) / 4;          // 12500

  k_deg<<<be, 256, 0, stream>>>(row, deg, e);
  k_dis<<<bn, 256, 0, stream>>>(deg, dis, n);
  k_scan_block<<<bn, 256, 0, stream>>>(deg, rp, blk, n);
  k_scan_top<<<1, 256, 0, stream>>>(blk, bn);
  k_scan_add<<<bn, 256, 0, stream>>>(rp, blk, n);
  k_fill<<<be, 256, 0, stream>>>(row, col, dis, rp, cur, cw, e);

  k_drop<<<bd, 256, 0, stream>>>(x, xa, dk[0][0], dk[0][1], n * 64, half);
  k_conv<64, true,  true ><<<bc, 256, 0, stream>>>(xa, rp, cw, W0,  b0, xb, dk[1][0], dk[1][1], half, n);
  k_conv<64, true,  true ><<<bc, 256, 0, stream>>>(xb, rp, cw, W1f, b1, xa, dk[2][0], dk[2][1], half, n);
  k_conv<32, false, false><<<bc, 256, 0, stream>>>(xa, rp, cw, W2,  b2, out, 0u, 0u, half, n);
}

// Round 2
// 388.565 us; speedup vs baseline: 1.5736x; 1.5736x over previous
//
#include <hip/hip_runtime.h>
#include <stdint.h>

#define THREEFRY_PARTITIONABLE 1

__host__ __device__ inline void tf2x32(uint32_t k0, uint32_t k1,
                                       uint32_t x0, uint32_t x1,
                                       uint32_t* o0, uint32_t* o1) {
  const uint32_t ks2 = k0 ^ k1 ^ 0x1BD11BDAu;
#define ROTL(v, s) (((v) << (s)) | ((v) >> (32 - (s))))
#define RND(r) do { x0 += x1; x1 = ROTL(x1, r); x1 ^= x0; } while (0)
  x0 += k0; x1 += k1;
  RND(13); RND(15); RND(26); RND(6);
  x0 += k1; x1 += ks2 + 1u;
  RND(17); RND(29); RND(16); RND(24);
  x0 += ks2; x1 += k0 + 2u;
  RND(13); RND(15); RND(26); RND(6);
  x0 += k0; x1 += k1 + 3u;
  RND(17); RND(29); RND(16); RND(24);
  x0 += k1; x1 += ks2 + 4u;
  RND(13); RND(15); RND(26); RND(6);
  x0 += ks2; x1 += k0 + 5u;
  *o0 = x0; *o1 = x1;
#undef RND
#undef ROTL
}

__device__ inline bool drop_keep(uint32_t k0, uint32_t k1, uint32_t idx) {
  uint32_t o0, o1;
  tf2x32(k0, k1, 0u, idx, &o0, &o1);
  uint32_t bits = o0 ^ o1;
  float u = __uint_as_float((bits >> 9) | 0x3f800000u) - 1.0f;
  return u < 0.4f;
}

__global__ void k_deg(const int* __restrict__ row, int* __restrict__ deg, int e) {
  int i = blockIdx.x * 256 + threadIdx.x;
  if (i < e) atomicAdd(&deg[row[i]], 1);
}

// inclusive scan of 256-chunks; chunk scans into rp[i+1], block totals into blksum
__global__ void k_scan_block(const int* __restrict__ deg, int* __restrict__ rp,
                             int* __restrict__ blksum, int n) {
  __shared__ int sm[256];
  int i = blockIdx.x * 256 + threadIdx.x;
  int v = (i < n) ? deg[i] : 0;
  sm[threadIdx.x] = v;
  __syncthreads();
  for (int off = 1; off < 256; off <<= 1) {
    int t = (threadIdx.x >= off) ? sm[threadIdx.x - off] : 0;
    __syncthreads();
    sm[threadIdx.x] += t;
    __syncthreads();
  }
  if (i < n) rp[i + 1] = sm[threadIdx.x];
  if (threadIdx.x == 255) blksum[blockIdx.x] = sm[255];
}

__global__ void k_scan_top(int* __restrict__ blk, int nblk) {
  __shared__ int sm[256];
  int v = (threadIdx.x < nblk) ? blk[threadIdx.x] : 0;
  sm[threadIdx.x] = v;
  __syncthreads();
  for (int off = 1; off < 256; off <<= 1) {
    int t = (threadIdx.x >= off) ? sm[threadIdx.x - off] : 0;
    __syncthreads();
    sm[threadIdx.x] += t;
    __syncthreads();
  }
  if (threadIdx.x < nblk) blk[threadIdx.x] = sm[threadIdx.x] - v;
}

__global__ void k_scan_add(int* __restrict__ rp, const int* __restrict__ blk, int n) {
  int i = blockIdx.x * 256 + threadIdx.x;
  if (i == 0) rp[0] = 0;
  if (i < n) rp[i + 1] += blk[i >> 8];
}

// CSR fill with inline weight: w = -rsqrt(deg[r])*rsqrt(deg[c]) (0 if deg[c]==0)
__global__ void k_fill(const int* __restrict__ row, const int* __restrict__ col,
                       const int* __restrict__ deg, const int* __restrict__ rp,
                       int* __restrict__ cur, int2* __restrict__ cw, int e) {
  int i = blockIdx.x * 256 + threadIdx.x;
  if (i < e) {
    int r = row[i], c = col[i];
    int pos = rp[r] + atomicAdd(&cur[r], 1);
    int dc = deg[c];
    float w = (dc > 0) ? -rsqrtf((float)deg[r]) * rsqrtf((float)dc) : 0.0f;
    cw[pos] = make_int2(c, __float_as_int(w));
  }
}

__global__ void k_drop(const float* __restrict__ x, float* __restrict__ y,
                       uint32_t k0, uint32_t k1, int n) {
  int i = blockIdx.x * 256 + threadIdx.x;
  if (i < n) y[i] = drop_keep(k0, k1, (uint32_t)i) ? x[i] * 2.5f : 0.0f;
}

// Fused conv: Tx1 = L_hat @ xd (CSR gather, 1 wave/row, 8-deep edge batching),
// then out = xd@W[0] + Tx1@W[1] + b, optional relu, optional next-layer dropout.
template<int COUT, bool RELU, bool DROPN>
__global__ __launch_bounds__(256) void k_conv(
    const float* __restrict__ xd, const int* __restrict__ rp,
    const int2* __restrict__ cw, const float* __restrict__ W,
    const float* __restrict__ b, float* __restrict__ out,
    uint32_t nk0, uint32_t nk1, int n) {
  __shared__ float Ws[2 * 64 * COUT];
  __shared__ float xs[4][64];
  __shared__ float ps[4][64];
  for (int i = threadIdx.x; i < 2 * 64 * COUT; i += 256) Ws[i] = W[i];
  const int row0 = blockIdx.x * 4;
  const int rl = threadIdx.x >> 6;   // local row (one wave per row)
  const int t  = threadIdx.x & 63;   // feature lane
  const int r  = row0 + rl;
  if (r < n) {
    xs[rl][t] = xd[(size_t)r * 64 + t];
    float acc = 0.0f;
    const int ee0 = rp[r];
    const int e1  = rp[r + 1];
    // 8-deep batched gather: 8 wave-uniform cw loads (64B contiguous), then
    // 8 independent 256B coalesced x-row gathers in flight, then 8 FMAs.
    for (int ee = ee0; ee < e1; ee += 8) {
      int   c[8];
      float w[8];
      #pragma unroll
      for (int j = 0; j < 8; ++j) {
        int idx = ee + j;
        int2 v = cw[idx < e1 ? idx : ee0];   // row nonempty here (ee0 < e1)
        c[j] = v.x;
        w[j] = (idx < e1) ? __int_as_float(v.y) : 0.0f;
      }
      float xv[8];
      #pragma unroll
      for (int j = 0; j < 8; ++j) xv[j] = xd[(size_t)c[j] * 64 + t];
      #pragma unroll
      for (int j = 0; j < 8; ++j) acc = fmaf(w[j], xv[j], acc);
    }
    ps[rl][t] = acc;
  }
  __syncthreads();
  if (threadIdx.x < 4 * COUT) {
    const int rl2 = threadIdx.x / COUT;
    const int o   = threadIdx.x % COUT;
    const int rr  = row0 + rl2;
    if (rr < n) {
      float v = b[o];
      const float* W0s = Ws;
      const float* W1s = Ws + 64 * COUT;
      #pragma unroll
      for (int k = 0; k < 64; ++k) {
        v = fmaf(xs[rl2][k], W0s[k * COUT + o], v);
        v = fmaf(ps[rl2][k], W1s[k * COUT + o], v);
      }
      if (RELU) v = fmaxf(v, 0.0f);
      if (DROPN) {
        if (drop_keep(nk0, nk1, (uint32_t)(rr * 64 + o))) v *= 2.5f;
        else v = 0.0f;
      }
      out[(size_t)rr * COUT + o] = v;
    }
  }
}

extern "C" void kernel_launch(void* const* d_in, const int* in_sizes, int n_in,
                              void* d_out, int out_size, void* d_ws, size_t ws_size,
                              hipStream_t stream) {
  const float* x   = (const float*)d_in[0];
  const int*   ei  = (const int*)d_in[1];
  const float* W0  = (const float*)d_in[2];
  const float* b0  = (const float*)d_in[3];
  const float* W1f = (const float*)d_in[4];
  const float* b1  = (const float*)d_in[5];
  const float* W2  = (const float*)d_in[6];
  const float* b2  = (const float*)d_in[7];
  float* out = (float*)d_out;

  const int n = in_sizes[0] / 64;   // 50000
  const int e = in_sizes[1] / 2;    // 800000
  const int* row = ei;
  const int* col = ei + e;

  size_t off = 0;
  auto carve = [&](size_t elems) {
    size_t o = off;
    off += (elems + 255) & ~(size_t)255;
    return o;
  };
  int* base = (int*)d_ws;
  int*   deg = base + carve(n);
  int*   rp  = base + carve((size_t)n + 1);
  int*   cur = base + carve(n);
  int*   blk = base + carve(256);
  int2*  cw  = (int2*)(base + carve((size_t)e * 2));
  float* xa  = (float*)(base + carve((size_t)n * 64));
  float* xb  = (float*)(base + carve((size_t)n * 64));
  (void)ws_size;

  // dropout keys: fold_in(jax.random.key(1), i) = threefry2x32([0,1],[0,i])
  uint32_t dk[3][2];
  for (uint32_t i = 0; i < 3; ++i) tf2x32(0u, 1u, 0u, i, &dk[i][0], &dk[i][1]);

  hipMemsetAsync(deg, 0, (size_t)n * 4, stream);
  hipMemsetAsync(cur, 0, (size_t)n * 4, stream);

  const int be = (e + 255) / 256;      // 3125
  const int bn = (n + 255) / 256;      // 196
  const int bd = ((n * 64) + 255) / 256;
  const int bc = (n + 3) / 4;          // 12500

  k_deg<<<be, 256, 0, stream>>>(row, deg, e);
  k_scan_block<<<bn, 256, 0, stream>>>(deg, rp, blk, n);
  k_scan_top<<<1, 256, 0, stream>>>(blk, bn);
  k_scan_add<<<bn, 256, 0, stream>>>(rp, blk, n);
  k_fill<<<be, 256, 0, stream>>>(row, col, deg, rp, cur, cw, e);

  k_drop<<<bd, 256, 0, stream>>>(x, xa, dk[0][0], dk[0][1], n * 64);
  k_conv<64, true,  true ><<<bc, 256, 0, stream>>>(xa, rp, cw, W0,  b0, xb, dk[1][0], dk[1][1], n);
  k_conv<64, true,  true ><<<bc, 256, 0, stream>>>(xb, rp, cw, W1f, b1, xa, dk[2][0], dk[2][1], n);
  k_conv<32, false, false><<<bc, 256, 0, stream>>>(xa, rp, cw, W2,  b2, out, 0u, 0u, n);
}